// Round 17
// baseline (134.505 us; speedup 1.0000x reference)
//
#include <hip/hip_runtime.h>

// Multiresolution hash encoding, MI355X. Round 17: block-coop coarse fill.
// R16 ledger: wall = per-CU address/L1-transaction path (~0.3 addr/cyc/CU,
// invariant across 450/285/86MB FETCH regimes). Last structural waste:
// (a) both waves of a bin filled separate LDS copies of the same 845 entries
//     -> one shared array per bin, 128-thread coop fill + __syncthreads;
// (b) static LDS halves 27136->13568, lifting the fused kernel (incl. fine
//     blocks, which share the static alloc) from 5 to 6+ blocks/CU;
// (c) launch_bounds(256,6) to claim the extra block (VGPR 40 << 85 budget).

constexpr int      kT      = 524288;     // 2^19 rows per level
constexpr unsigned kMask   = kT - 1;
constexpr int      kB      = 262144;
constexpr unsigned kP1     = 2654435761u;
constexpr unsigned kP2     = 805459861u;
constexpr int      kBins   = 4096;
constexpr int      kCap    = 128;        // slots per bin (2 waves)
constexpr int      kOvfCap = 65536;      // overflow list capacity (never filled)
constexpr int      kCoopTot = 845;       // per-BIN LDS f32x2 entries (8 coarse levels)

typedef float f32x4 __attribute__((ext_vector_type(4)));
typedef float f32x2 __attribute__((ext_vector_type(2)));

__device__ __forceinline__ unsigned morton12(float x0, float x1, float x2) {
    unsigned a = min(15u, (unsigned)(x0 * 16.0f));
    unsigned b = min(15u, (unsigned)(x1 * 16.0f));
    unsigned c = min(15u, (unsigned)(x2 * 16.0f));
    unsigned key = 0;
#pragma unroll
    for (int i = 3; i >= 0; --i)
        key = (key << 3) | (((a >> i) & 1u) << 2) | (((b >> i) & 1u) << 1) | ((c >> i) & 1u);
    return key;
}

// ---- direct path: one level, pair-load structure (dim0 prime==1) ----
__device__ __forceinline__ f32x2 direct_level(const float x0, const float x1, const float x2,
                                              const float res,
                                              const f32x4* __restrict__ tab4) {
    const float s0 = x0 * res, s1 = x1 * res, s2 = x2 * res;
    const float f0 = floorf(s0), f1 = floorf(s1), f2 = floorf(s2);
    const float r0 = s0 - f0, r1 = s1 - f1, r2 = s2 - f2;
    const unsigned c0 = (unsigned)f0;
    const unsigned h1a = (unsigned)f1 * kP1, h1b = h1a + kP1;
    const unsigned h2a = (unsigned)f2 * kP2, h2b = h2a + kP2;
    const float w0a = 1.0f - r0, w1a = 1.0f - r1, w2a = 1.0f - r2;
    float a0 = 0.0f, a1 = 0.0f;
#pragma unroll
    for (int q = 0; q < 4; ++q) {  // (y,z) corner combos
        const unsigned g = ((q & 1) ? h1b : h1a) ^ ((q & 2) ? h2b : h2a);
        const unsigned i0 = (c0 ^ g) & kMask;
        const unsigned i1 = ((c0 + 1u) ^ g) & kMask;
        const f32x4 A = tab4[i0 >> 1];
        const f32x4 B = tab4[i1 >> 1];  // same line as A when c0 even
        const float p0x = (i0 & 1) ? A.z : A.x;
        const float p0y = (i0 & 1) ? A.w : A.y;
        const float p1x = (i1 & 1) ? B.z : B.x;
        const float p1y = (i1 & 1) ? B.w : B.y;
        const float wyz = ((q & 1) ? r1 : w1a) * ((q & 2) ? r2 : w2a);
        const float wl = wyz * w0a;
        const float wr = wyz * r0;
        a0 = fmaf(wl, p0x, fmaf(wr, p1x, a0));
        a1 = fmaf(wl, p0y, fmaf(wr, p1y, a1));
    }
    f32x2 r; r.x = a0; r.y = a1;
    return r;
}

// ---- fine path with exec-masked B-loads (only odd-c0 lanes issue them) ----
__device__ __forceinline__ f32x2 direct_level_masked(const float x0, const float x1, const float x2,
                                                     const float res,
                                                     const f32x4* __restrict__ tab4) {
    const float s0 = x0 * res, s1 = x1 * res, s2 = x2 * res;
    const float f0 = floorf(s0), f1 = floorf(s1), f2 = floorf(s2);
    const float r0 = s0 - f0, r1 = s1 - f1, r2 = s2 - f2;
    const unsigned c0 = (unsigned)f0;
    const unsigned h1a = (unsigned)f1 * kP1, h1b = h1a + kP1;
    const unsigned h2a = (unsigned)f2 * kP2, h2b = h2a + kP2;
    const float w0a = 1.0f - r0, w1a = 1.0f - r1, w2a = 1.0f - r2;

    unsigned i0[4], i1[4];
#pragma unroll
    for (int q = 0; q < 4; ++q) {
        const unsigned g = ((q & 1) ? h1b : h1a) ^ ((q & 2) ? h2b : h2a);
        i0[q] = (c0 ^ g) & kMask;
        i1[q] = ((c0 + 1u) ^ g) & kMask;
    }
    f32x4 A[4];
#pragma unroll
    for (int q = 0; q < 4; ++q) A[q] = tab4[i0[q] >> 1];
    const bool odd = (c0 & 1u) != 0u;
    f32x4 Bv[4];  // only defined for odd lanes; selected away otherwise
    if (odd) {
#pragma unroll
        for (int q = 0; q < 4; ++q) Bv[q] = tab4[i1[q] >> 1];
    }
    float a0 = 0.0f, a1 = 0.0f;
#pragma unroll
    for (int q = 0; q < 4; ++q) {
        const float p0x = (i0[q] & 1) ? A[q].z : A[q].x;
        const float p0y = (i0[q] & 1) ? A[q].w : A[q].y;
        // even c0: i1>>1 == i0>>1, entry is the (i1&1) half of A
        const float ex = (i1[q] & 1) ? A[q].z : A[q].x;
        const float ey = (i1[q] & 1) ? A[q].w : A[q].y;
        const float bx_ = (i1[q] & 1) ? Bv[q].z : Bv[q].x;
        const float by_ = (i1[q] & 1) ? Bv[q].w : Bv[q].y;
        const float p1x = odd ? bx_ : ex;
        const float p1y = odd ? by_ : ey;
        const float wyz = ((q & 1) ? r1 : w1a) * ((q & 2) ? r2 : w2a);
        const float wl = wyz * w0a;
        const float wr = wyz * r0;
        a0 = fmaf(wl, p0x, fmaf(wr, p1x, a0));
        a1 = fmaf(wl, p0y, fmaf(wr, p1y, a1));
    }
    f32x2 r; r.x = a0; r.y = a1;
    return r;
}

// ---- full 16-level direct body (fallback / cleanup paths) ----
__device__ __forceinline__ void hashenc_body(const float x0, const float x1, const float x2,
                                             const f32x4* __restrict__ tab4base,
                                             f32x4* __restrict__ out, const unsigned sid) {
    f32x4 o[8];
    // floor(16 * b^l), b = 2^(1/3): rounding-traced, verified (absmax 4.8e-7)
    constexpr float kResF[16] = {16, 20, 25, 32, 40, 50, 64, 80,
                                 101, 128, 161, 203, 256, 322, 406, 512};
#pragma unroll
    for (int l = 0; l < 16; ++l) {
        const f32x2 r = direct_level(x0, x1, x2, kResF[l], tab4base + (size_t)l * (kT / 2));
        if (l & 1) { o[l >> 1].z = r.x; o[l >> 1].w = r.y; }
        else       { o[l >> 1].x = r.x; o[l >> 1].y = r.y; }
    }
    f32x4* op = out + (size_t)sid * 8;
#pragma unroll
    for (int k = 0; k < 8; ++k) __builtin_nontemporal_store(o[k], op + k);
}

// ---- cooperative coarse-level fill: 128 threads per bin ----
template <int L, int N, int RES, int OFF>
__device__ __forceinline__ void coop_fill128(const unsigned t,
                                             const unsigned bx, const unsigned by, const unsigned bz,
                                             const f32x2* __restrict__ tab2,
                                             f32x2* __restrict__ wlds) {
    const unsigned lo0 = (bx * RES) >> 4, lo1 = (by * RES) >> 4, lo2 = (bz * RES) >> 4;
    const unsigned h1 = lo1 * kP1, h2 = lo2 * kP2;
    constexpr int NC = N * N * N;
#pragma unroll
    for (int k = 0; k < (NC + 127) / 128; ++k) {
        const int e = (int)t + 128 * k;
        if (e < NC) {
            const unsigned dx = (unsigned)e / (N * N);
            const unsigned rem = (unsigned)e % (N * N);
            const unsigned dy = rem / N, dz = rem % N;
            const unsigned idx = ((lo0 + dx) ^ (h1 + dy * kP1) ^ (h2 + dz * kP2)) & kMask;
            wlds[OFF + e] = tab2[(size_t)L * kT + idx];
        }
    }
}

template <int N, int RES, int OFF>
__device__ __forceinline__ f32x2 coop_interp(const float x0, const float x1, const float x2,
                                             const unsigned bx, const unsigned by, const unsigned bz,
                                             const f32x2* __restrict__ wlds) {
    const float res = (float)RES;
    const float s0 = x0 * res, s1 = x1 * res, s2 = x2 * res;
    const float f0 = floorf(s0), f1 = floorf(s1), f2 = floorf(s2);
    const float r0 = s0 - f0, r1 = s1 - f1, r2 = s2 - f2;
    const unsigned lo0 = (bx * RES) >> 4, lo1 = (by * RES) >> 4, lo2 = (bz * RES) >> 4;
    // valid lanes: indices provably in [0, N-2]; min() guards defensive cases
    const unsigned i0 = min((unsigned)f0 - lo0, (unsigned)(N - 2));
    const unsigned i1 = min((unsigned)f1 - lo1, (unsigned)(N - 2));
    const unsigned i2 = min((unsigned)f2 - lo2, (unsigned)(N - 2));
    const int s00 = OFF + (int)(i0 * (N * N) + i1 * N + i2);
    const f32x2 c000 = wlds[s00],             c001 = wlds[s00 + 1];
    const f32x2 c010 = wlds[s00 + N],         c011 = wlds[s00 + N + 1];
    const f32x2 c100 = wlds[s00 + N * N],     c101 = wlds[s00 + N * N + 1];
    const f32x2 c110 = wlds[s00 + N * N + N], c111 = wlds[s00 + N * N + N + 1];
    const float w0a = 1.f - r0, w1a = 1.f - r1, w2a = 1.f - r2;
    const float w00 = w0a * w1a, w01 = w0a * r1, w10 = r0 * w1a, w11 = r0 * r1;
    float a0 = w00 * w2a * c000.x;
    float a1 = w00 * w2a * c000.y;
    a0 = fmaf(w00 * r2,  c001.x, a0); a1 = fmaf(w00 * r2,  c001.y, a1);
    a0 = fmaf(w01 * w2a, c010.x, a0); a1 = fmaf(w01 * w2a, c010.y, a1);
    a0 = fmaf(w01 * r2,  c011.x, a0); a1 = fmaf(w01 * r2,  c011.y, a1);
    a0 = fmaf(w10 * w2a, c100.x, a0); a1 = fmaf(w10 * w2a, c100.y, a1);
    a0 = fmaf(w10 * r2,  c101.x, a0); a1 = fmaf(w10 * r2,  c101.y, a1);
    a0 = fmaf(w11 * w2a, c110.x, a0); a1 = fmaf(w11 * w2a, c110.y, a1);
    a0 = fmaf(w11 * r2,  c111.x, a0); a1 = fmaf(w11 * r2,  c111.y, a1);
    f32x2 r; r.x = a0; r.y = a1;
    return r;
}

__global__ __launch_bounds__(256) void scatter_kernel(const float* __restrict__ x,
                                                      unsigned* __restrict__ cnt,
                                                      f32x4* __restrict__ xsort,
                                                      f32x4* __restrict__ ovf) {
    const int i = blockIdx.x * 256 + threadIdx.x;
    const float x0 = x[3 * i], x1 = x[3 * i + 1], x2 = x[3 * i + 2];
    const unsigned key = morton12(x0, x1, x2);
    const unsigned slot = atomicAdd(&cnt[key], 1u);
    f32x4 v;
    v.x = x0; v.y = x1; v.z = x2; v.w = __uint_as_float((unsigned)i);
    if (slot < (unsigned)kCap) {
        xsort[key * kCap + slot] = v;
    } else {
        const unsigned o = atomicAdd(&cnt[kBins], 1u);
        if (o < (unsigned)kOvfCap) ovf[o] = v;  // kOvfCap=64K: cannot fill (P~0)
    }
}

// ---- fused main: blocks <2048 = fine (XCD-pinned level), >=2048 = coarse coop ----
__global__ __launch_bounds__(256, 6) void hashenc_main(const float* __restrict__ x,
                                                       const f32x4* __restrict__ xsort,
                                                       const unsigned* __restrict__ cnt,
                                                       const f32x2* __restrict__ tab2,
                                                       const f32x4* __restrict__ tab4base,
                                                       f32x4* __restrict__ out) {
    __shared__ f32x2 lds[2][kCoopTot];   // one array per BIN (13520 B/block)
    const int tid = threadIdx.x;
    const int b = (int)blockIdx.x;

    if (b < 2048) {
        // ---- FINE: level 8+(b&7) pinned to XCD b&7; 4MB table L2-resident ----
        constexpr float kFineRes[8] = {101, 128, 161, 203, 256, 322, 406, 512};
        const int j = b & 7;                  // XCD id == level index
        const int chunk = b >> 3;             // 0..255
        const float res = kFineRes[j];
        const f32x4* __restrict__ tab4 = tab4base + (size_t)(8 + j) * (kT / 2);
        f32x2* __restrict__ out2 = (f32x2*)out;
        const int sbase = chunk * 1024 + tid;
#pragma unroll
        for (int it = 0; it < 4; ++it) {
            const int s = sbase + 256 * it;
            const float x0 = x[3 * s + 0];
            const float x1 = x[3 * s + 1];
            const float x2 = x[3 * s + 2];
            const f32x2 r = direct_level_masked(x0, x1, x2, res, tab4);
            __builtin_nontemporal_store(r, out2 + (size_t)s * 16 + 8 + j);
        }
        return;
    }

    // ---- COARSE: levels 0-7 coop; block = 2 bins, 128 threads fill each ----
    const int c = b - 2048;
    // chunked XCD swizzle: XCD k owns a contiguous Morton chunk (2048 = 8*256)
    const int bid = (int)((c & 7) * 256 + (c >> 3));
    const int gs  = bid * 256 + tid;
    const int bin = gs >> 7;          // kCap = 128; tid<128 -> binA, else binB
    const int sl  = gs & (kCap - 1);
    const unsigned n = min(cnt[bin], (unsigned)kCap);
    const bool valid = (unsigned)sl < n;
    const f32x4 v = xsort[gs];        // in-bounds always; garbage if !valid

    const unsigned key = (unsigned)bin;
    const unsigned bx = ((key >> 2) & 1) | ((key >> 4) & 2) | ((key >> 6) & 4) | ((key >> 8) & 8);
    const unsigned by = ((key >> 1) & 1) | ((key >> 3) & 2) | ((key >> 5) & 4) | ((key >> 7) & 8);
    const unsigned bz = ((key     ) & 1) | ((key >> 2) & 2) | ((key >> 4) & 4) | ((key >> 6) & 8);

    f32x2* wlds = lds[tid >> 7];
    const unsigned t = (unsigned)(tid & 127);

    // Phase 1: 128-thread cooperative fill of this bin's corner sets
    coop_fill128<0, 2, 16,   0>(t, bx, by, bz, tab2, wlds);
    coop_fill128<1, 4, 20,   8>(t, bx, by, bz, tab2, wlds);
    coop_fill128<2, 4, 25,  72>(t, bx, by, bz, tab2, wlds);
    coop_fill128<3, 3, 32, 136>(t, bx, by, bz, tab2, wlds);
    coop_fill128<4, 5, 40, 163>(t, bx, by, bz, tab2, wlds);
    coop_fill128<5, 6, 50, 288>(t, bx, by, bz, tab2, wlds);
    coop_fill128<6, 5, 64, 504>(t, bx, by, bz, tab2, wlds);
    coop_fill128<7, 6, 80, 629>(t, bx, by, bz, tab2, wlds);

    __syncthreads();

    // Phase 2: interp + store, exec-masked to valid lanes
    if (valid) {
        const float x0 = v.x, x1 = v.y, x2 = v.z;
        f32x4 o0, o1, o2, o3;
        { const f32x2 r = coop_interp<2, 16,   0>(x0, x1, x2, bx, by, bz, wlds); o0.x = r.x; o0.y = r.y; }
        { const f32x2 r = coop_interp<4, 20,   8>(x0, x1, x2, bx, by, bz, wlds); o0.z = r.x; o0.w = r.y; }
        { const f32x2 r = coop_interp<4, 25,  72>(x0, x1, x2, bx, by, bz, wlds); o1.x = r.x; o1.y = r.y; }
        { const f32x2 r = coop_interp<3, 32, 136>(x0, x1, x2, bx, by, bz, wlds); o1.z = r.x; o1.w = r.y; }
        { const f32x2 r = coop_interp<5, 40, 163>(x0, x1, x2, bx, by, bz, wlds); o2.x = r.x; o2.y = r.y; }
        { const f32x2 r = coop_interp<6, 50, 288>(x0, x1, x2, bx, by, bz, wlds); o2.z = r.x; o2.w = r.y; }
        { const f32x2 r = coop_interp<5, 64, 504>(x0, x1, x2, bx, by, bz, wlds); o3.x = r.x; o3.y = r.y; }
        { const f32x2 r = coop_interp<6, 80, 629>(x0, x1, x2, bx, by, bz, wlds); o3.z = r.x; o3.w = r.y; }

        f32x4* op = out + (size_t)__float_as_uint(v.w) * 8;
        __builtin_nontemporal_store(o0, op + 0);
        __builtin_nontemporal_store(o1, op + 1);
        __builtin_nontemporal_store(o2, op + 2);
        __builtin_nontemporal_store(o3, op + 3);
    }
}

// Overflow cleanup in its own dispatch (~always zero work; correctness net).
__global__ __launch_bounds__(256) void cleanup_kernel(const f32x4* __restrict__ ovf,
                                                      const unsigned* __restrict__ cnt,
                                                      const f32x4* __restrict__ tab4base,
                                                      f32x4* __restrict__ out) {
    const unsigned oc = min(cnt[kBins], (unsigned)kOvfCap);
    for (unsigned j = threadIdx.x; j < oc; j += 256) {
        const f32x4 v = ovf[j];
        hashenc_body(v.x, v.y, v.z, tab4base, out, __float_as_uint(v.w));
    }
}

__global__ __launch_bounds__(256, 4) void hashenc_direct(const float* __restrict__ x,
                                                         const f32x4* __restrict__ tab4base,
                                                         f32x4* __restrict__ out) {
    const int i = blockIdx.x * 256 + threadIdx.x;
    hashenc_body(x[3 * i], x[3 * i + 1], x[3 * i + 2], tab4base, out, (unsigned)i);
}

extern "C" void kernel_launch(void* const* d_in, const int* in_sizes, int n_in,
                              void* d_out, int out_size, void* d_ws, size_t ws_size,
                              hipStream_t stream) {
    const float*  x    = (const float*)d_in[0];
    const f32x2*  tab2 = (const f32x2*)d_in[1];
    const f32x4*  tab4 = (const f32x4*)d_in[1];
    f32x4*        out  = (f32x4*)d_out;

    const size_t cntBytes   = (size_t)(kBins + 16) * 4;       // counters + ovf count
    const size_t ovfBytes   = (size_t)kOvfCap * 16;           // 1 MB
    const size_t xsortBytes = (size_t)kBins * kCap * 16;      // 8 MB
    const size_t need = cntBytes + ovfBytes + xsortBytes;

    if (ws_size >= need) {
        unsigned* cnt   = (unsigned*)d_ws;
        f32x4*    ovf   = (f32x4*)((char*)d_ws + cntBytes);
        f32x4*    xsort = ovf + kOvfCap;
        hipMemsetAsync(cnt, 0, cntBytes, stream);
        scatter_kernel<<<kB / 256, 256, 0, stream>>>(x, cnt, xsort, ovf);
        hashenc_main<<<4096, 256, 0, stream>>>(x, xsort, cnt, tab2, tab4, out);
        cleanup_kernel<<<1, 256, 0, stream>>>(ovf, cnt, tab4, out);
    } else {
        hashenc_direct<<<kB / 256, 256, 0, stream>>>(x, tab4, out);
    }
}

// Round 18
// 132.000 us; speedup vs baseline: 1.0190x; 1.0190x over previous
//
#include <hip/hip_runtime.h>

// Multiresolution hash encoding, MI355X. Round 18: revert to R16 (measured best,
// 132.2us). Floor triangulated across R14/R16/R17: main ~110us invariant over
// occupancy 8-76%, VGPR 32-136, FETCH 86-450MB => per-CU random-gather
// address-path bound (~0.25 lane-addr/cyc/CU). All structural levers applied:
// pair-loads (dim0 prime==1), Morton bucketing, XCD level-pinning (L2-resident
// fine tables), exec-masked B-loads, coop LDS staging of coarse levels.

constexpr int      kT      = 524288;     // 2^19 rows per level
constexpr unsigned kMask   = kT - 1;
constexpr int      kB      = 262144;
constexpr unsigned kP1     = 2654435761u;
constexpr unsigned kP2     = 805459861u;
constexpr int      kBins   = 4096;
constexpr int      kCap    = 128;        // slots per bin (2 waves)
constexpr int      kOvfCap = 65536;      // overflow list capacity (never filled)
constexpr int      kCoopTot = 845;       // per-wave LDS f32x2 entries (8 coarse levels)

typedef float f32x4 __attribute__((ext_vector_type(4)));
typedef float f32x2 __attribute__((ext_vector_type(2)));

__device__ __forceinline__ unsigned morton12(float x0, float x1, float x2) {
    unsigned a = min(15u, (unsigned)(x0 * 16.0f));
    unsigned b = min(15u, (unsigned)(x1 * 16.0f));
    unsigned c = min(15u, (unsigned)(x2 * 16.0f));
    unsigned key = 0;
#pragma unroll
    for (int i = 3; i >= 0; --i)
        key = (key << 3) | (((a >> i) & 1u) << 2) | (((b >> i) & 1u) << 1) | ((c >> i) & 1u);
    return key;
}

// ---- direct path: one level, pair-load structure (dim0 prime==1) ----
__device__ __forceinline__ f32x2 direct_level(const float x0, const float x1, const float x2,
                                              const float res,
                                              const f32x4* __restrict__ tab4) {
    const float s0 = x0 * res, s1 = x1 * res, s2 = x2 * res;
    const float f0 = floorf(s0), f1 = floorf(s1), f2 = floorf(s2);
    const float r0 = s0 - f0, r1 = s1 - f1, r2 = s2 - f2;
    const unsigned c0 = (unsigned)f0;
    const unsigned h1a = (unsigned)f1 * kP1, h1b = h1a + kP1;
    const unsigned h2a = (unsigned)f2 * kP2, h2b = h2a + kP2;
    const float w0a = 1.0f - r0, w1a = 1.0f - r1, w2a = 1.0f - r2;
    float a0 = 0.0f, a1 = 0.0f;
#pragma unroll
    for (int q = 0; q < 4; ++q) {  // (y,z) corner combos
        const unsigned g = ((q & 1) ? h1b : h1a) ^ ((q & 2) ? h2b : h2a);
        const unsigned i0 = (c0 ^ g) & kMask;
        const unsigned i1 = ((c0 + 1u) ^ g) & kMask;
        const f32x4 A = tab4[i0 >> 1];
        const f32x4 B = tab4[i1 >> 1];  // same line as A when c0 even
        const float p0x = (i0 & 1) ? A.z : A.x;
        const float p0y = (i0 & 1) ? A.w : A.y;
        const float p1x = (i1 & 1) ? B.z : B.x;
        const float p1y = (i1 & 1) ? B.w : B.y;
        const float wyz = ((q & 1) ? r1 : w1a) * ((q & 2) ? r2 : w2a);
        const float wl = wyz * w0a;
        const float wr = wyz * r0;
        a0 = fmaf(wl, p0x, fmaf(wr, p1x, a0));
        a1 = fmaf(wl, p0y, fmaf(wr, p1y, a1));
    }
    f32x2 r; r.x = a0; r.y = a1;
    return r;
}

// ---- fine path with exec-masked B-loads (only odd-c0 lanes issue them) ----
__device__ __forceinline__ f32x2 direct_level_masked(const float x0, const float x1, const float x2,
                                                     const float res,
                                                     const f32x4* __restrict__ tab4) {
    const float s0 = x0 * res, s1 = x1 * res, s2 = x2 * res;
    const float f0 = floorf(s0), f1 = floorf(s1), f2 = floorf(s2);
    const float r0 = s0 - f0, r1 = s1 - f1, r2 = s2 - f2;
    const unsigned c0 = (unsigned)f0;
    const unsigned h1a = (unsigned)f1 * kP1, h1b = h1a + kP1;
    const unsigned h2a = (unsigned)f2 * kP2, h2b = h2a + kP2;
    const float w0a = 1.0f - r0, w1a = 1.0f - r1, w2a = 1.0f - r2;

    unsigned i0[4], i1[4];
#pragma unroll
    for (int q = 0; q < 4; ++q) {
        const unsigned g = ((q & 1) ? h1b : h1a) ^ ((q & 2) ? h2b : h2a);
        i0[q] = (c0 ^ g) & kMask;
        i1[q] = ((c0 + 1u) ^ g) & kMask;
    }
    f32x4 A[4];
#pragma unroll
    for (int q = 0; q < 4; ++q) A[q] = tab4[i0[q] >> 1];
    const bool odd = (c0 & 1u) != 0u;
    f32x4 Bv[4];  // only defined for odd lanes; selected away otherwise
    if (odd) {
#pragma unroll
        for (int q = 0; q < 4; ++q) Bv[q] = tab4[i1[q] >> 1];
    }
    float a0 = 0.0f, a1 = 0.0f;
#pragma unroll
    for (int q = 0; q < 4; ++q) {
        const float p0x = (i0[q] & 1) ? A[q].z : A[q].x;
        const float p0y = (i0[q] & 1) ? A[q].w : A[q].y;
        // even c0: i1>>1 == i0>>1, entry is the (i1&1) half of A
        const float ex = (i1[q] & 1) ? A[q].z : A[q].x;
        const float ey = (i1[q] & 1) ? A[q].w : A[q].y;
        const float bx_ = (i1[q] & 1) ? Bv[q].z : Bv[q].x;
        const float by_ = (i1[q] & 1) ? Bv[q].w : Bv[q].y;
        const float p1x = odd ? bx_ : ex;
        const float p1y = odd ? by_ : ey;
        const float wyz = ((q & 1) ? r1 : w1a) * ((q & 2) ? r2 : w2a);
        const float wl = wyz * w0a;
        const float wr = wyz * r0;
        a0 = fmaf(wl, p0x, fmaf(wr, p1x, a0));
        a1 = fmaf(wl, p0y, fmaf(wr, p1y, a1));
    }
    f32x2 r; r.x = a0; r.y = a1;
    return r;
}

// ---- full 16-level direct body (fallback / cleanup paths) ----
__device__ __forceinline__ void hashenc_body(const float x0, const float x1, const float x2,
                                             const f32x4* __restrict__ tab4base,
                                             f32x4* __restrict__ out, const unsigned sid) {
    f32x4 o[8];
    // floor(16 * b^l), b = 2^(1/3): rounding-traced, verified (absmax 4.8e-7)
    constexpr float kResF[16] = {16, 20, 25, 32, 40, 50, 64, 80,
                                 101, 128, 161, 203, 256, 322, 406, 512};
#pragma unroll
    for (int l = 0; l < 16; ++l) {
        const f32x2 r = direct_level(x0, x1, x2, kResF[l], tab4base + (size_t)l * (kT / 2));
        if (l & 1) { o[l >> 1].z = r.x; o[l >> 1].w = r.y; }
        else       { o[l >> 1].x = r.x; o[l >> 1].y = r.y; }
    }
    f32x4* op = out + (size_t)sid * 8;
#pragma unroll
    for (int k = 0; k < 8; ++k) __builtin_nontemporal_store(o[k], op + k);
}

// ---- cooperative coarse-level helpers (ranges validated R12/R13/R14) ----
template <int L, int N, int RES, int OFF>
__device__ __forceinline__ void coop_fill(const unsigned lane,
                                          const unsigned bx, const unsigned by, const unsigned bz,
                                          const f32x2* __restrict__ tab2,
                                          f32x2* __restrict__ wlds) {
    const unsigned lo0 = (bx * RES) >> 4, lo1 = (by * RES) >> 4, lo2 = (bz * RES) >> 4;
    const unsigned h1 = lo1 * kP1, h2 = lo2 * kP2;
    constexpr int NC = N * N * N;
#pragma unroll
    for (int k = 0; k < (NC + 63) / 64; ++k) {
        const int t = (int)lane + 64 * k;
        if (t < NC) {
            const unsigned dx = (unsigned)t / (N * N);
            const unsigned rem = (unsigned)t % (N * N);
            const unsigned dy = rem / N, dz = rem % N;
            const unsigned idx = ((lo0 + dx) ^ (h1 + dy * kP1) ^ (h2 + dz * kP2)) & kMask;
            wlds[OFF + t] = tab2[(size_t)L * kT + idx];
        }
    }
}

template <int N, int RES, int OFF>
__device__ __forceinline__ f32x2 coop_interp(const float x0, const float x1, const float x2,
                                             const unsigned bx, const unsigned by, const unsigned bz,
                                             const f32x2* __restrict__ wlds) {
    const float res = (float)RES;
    const float s0 = x0 * res, s1 = x1 * res, s2 = x2 * res;
    const float f0 = floorf(s0), f1 = floorf(s1), f2 = floorf(s2);
    const float r0 = s0 - f0, r1 = s1 - f1, r2 = s2 - f2;
    const unsigned lo0 = (bx * RES) >> 4, lo1 = (by * RES) >> 4, lo2 = (bz * RES) >> 4;
    // valid lanes: indices provably in [0, N-2]; min() only guards garbage lanes
    const unsigned i0 = min((unsigned)f0 - lo0, (unsigned)(N - 2));
    const unsigned i1 = min((unsigned)f1 - lo1, (unsigned)(N - 2));
    const unsigned i2 = min((unsigned)f2 - lo2, (unsigned)(N - 2));
    const int s00 = OFF + (int)(i0 * (N * N) + i1 * N + i2);
    const f32x2 c000 = wlds[s00],             c001 = wlds[s00 + 1];
    const f32x2 c010 = wlds[s00 + N],         c011 = wlds[s00 + N + 1];
    const f32x2 c100 = wlds[s00 + N * N],     c101 = wlds[s00 + N * N + 1];
    const f32x2 c110 = wlds[s00 + N * N + N], c111 = wlds[s00 + N * N + N + 1];
    const float w0a = 1.f - r0, w1a = 1.f - r1, w2a = 1.f - r2;
    const float w00 = w0a * w1a, w01 = w0a * r1, w10 = r0 * w1a, w11 = r0 * r1;
    float a0 = w00 * w2a * c000.x;
    float a1 = w00 * w2a * c000.y;
    a0 = fmaf(w00 * r2,  c001.x, a0); a1 = fmaf(w00 * r2,  c001.y, a1);
    a0 = fmaf(w01 * w2a, c010.x, a0); a1 = fmaf(w01 * w2a, c010.y, a1);
    a0 = fmaf(w01 * r2,  c011.x, a0); a1 = fmaf(w01 * r2,  c011.y, a1);
    a0 = fmaf(w10 * w2a, c100.x, a0); a1 = fmaf(w10 * w2a, c100.y, a1);
    a0 = fmaf(w10 * r2,  c101.x, a0); a1 = fmaf(w10 * r2,  c101.y, a1);
    a0 = fmaf(w11 * w2a, c110.x, a0); a1 = fmaf(w11 * w2a, c110.y, a1);
    a0 = fmaf(w11 * r2,  c111.x, a0); a1 = fmaf(w11 * r2,  c111.y, a1);
    f32x2 r; r.x = a0; r.y = a1;
    return r;
}

__global__ __launch_bounds__(256) void scatter_kernel(const float* __restrict__ x,
                                                      unsigned* __restrict__ cnt,
                                                      f32x4* __restrict__ xsort,
                                                      f32x4* __restrict__ ovf) {
    const int i = blockIdx.x * 256 + threadIdx.x;
    const float x0 = x[3 * i], x1 = x[3 * i + 1], x2 = x[3 * i + 2];
    const unsigned key = morton12(x0, x1, x2);
    const unsigned slot = atomicAdd(&cnt[key], 1u);
    f32x4 v;
    v.x = x0; v.y = x1; v.z = x2; v.w = __uint_as_float((unsigned)i);
    if (slot < (unsigned)kCap) {
        xsort[key * kCap + slot] = v;
    } else {
        const unsigned o = atomicAdd(&cnt[kBins], 1u);
        if (o < (unsigned)kOvfCap) ovf[o] = v;  // kOvfCap=64K: cannot fill (P~0)
    }
}

// ---- fused main: blocks <2048 = fine (XCD-pinned level), >=2048 = coarse coop ----
__global__ __launch_bounds__(256, 5) void hashenc_main(const float* __restrict__ x,
                                                       const f32x4* __restrict__ xsort,
                                                       const unsigned* __restrict__ cnt,
                                                       const f32x2* __restrict__ tab2,
                                                       const f32x4* __restrict__ tab4base,
                                                       f32x4* __restrict__ out) {
    __shared__ f32x2 lds[4][kCoopTot];
    const int tid = threadIdx.x;
    const int b = (int)blockIdx.x;

    if (b < 2048) {
        // ---- FINE: level 8+(b&7) pinned to XCD b&7; 4MB table L2-resident ----
        constexpr float kFineRes[8] = {101, 128, 161, 203, 256, 322, 406, 512};
        const int j = b & 7;                  // XCD id == level index
        const int chunk = b >> 3;             // 0..255
        const float res = kFineRes[j];
        const f32x4* __restrict__ tab4 = tab4base + (size_t)(8 + j) * (kT / 2);
        f32x2* __restrict__ out2 = (f32x2*)out;
        const int sbase = chunk * 1024 + tid;
#pragma unroll
        for (int it = 0; it < 4; ++it) {
            const int s = sbase + 256 * it;
            const float x0 = x[3 * s + 0];
            const float x1 = x[3 * s + 1];
            const float x2 = x[3 * s + 2];
            const f32x2 r = direct_level_masked(x0, x1, x2, res, tab4);
            __builtin_nontemporal_store(r, out2 + (size_t)s * 16 + 8 + j);
        }
        return;
    }

    // ---- COARSE: R14 coop path (levels 0-7), writes row line 0 ----
    const int c = b - 2048;
    // chunked XCD swizzle: XCD k owns a contiguous Morton chunk (2048 = 8*256)
    const int bid = (int)((c & 7) * 256 + (c >> 3));
    const int gs  = bid * 256 + tid;
    const int bin = gs >> 7;          // kCap = 128
    const int sl  = gs & (kCap - 1);
    const unsigned n = min(cnt[bin], (unsigned)kCap);
    if ((unsigned)(sl & 64) >= n) return;   // wave-uniform early out
    const bool valid = (unsigned)sl < n;
    const f32x4 v = xsort[gs];
    const float x0 = valid ? v.x : 0.5f;    // garbage lanes -> benign coords
    const float x1 = valid ? v.y : 0.5f;
    const float x2 = valid ? v.z : 0.5f;

    const unsigned key = (unsigned)bin;
    const unsigned bx = ((key >> 2) & 1) | ((key >> 4) & 2) | ((key >> 6) & 4) | ((key >> 8) & 8);
    const unsigned by = ((key >> 1) & 1) | ((key >> 3) & 2) | ((key >> 5) & 4) | ((key >> 7) & 8);
    const unsigned bz = ((key     ) & 1) | ((key >> 2) & 2) | ((key >> 4) & 4) | ((key >> 6) & 8);

    f32x2* wlds = lds[tid >> 6];
    const unsigned lane = (unsigned)(tid & 63);

    coop_fill<0, 2, 16,   0>(lane, bx, by, bz, tab2, wlds);
    coop_fill<1, 4, 20,   8>(lane, bx, by, bz, tab2, wlds);
    coop_fill<2, 4, 25,  72>(lane, bx, by, bz, tab2, wlds);
    coop_fill<3, 3, 32, 136>(lane, bx, by, bz, tab2, wlds);
    coop_fill<4, 5, 40, 163>(lane, bx, by, bz, tab2, wlds);
    coop_fill<5, 6, 50, 288>(lane, bx, by, bz, tab2, wlds);
    coop_fill<6, 5, 64, 504>(lane, bx, by, bz, tab2, wlds);
    coop_fill<7, 6, 80, 629>(lane, bx, by, bz, tab2, wlds);

    f32x4 o0, o1, o2, o3;
    { const f32x2 r = coop_interp<2, 16,   0>(x0, x1, x2, bx, by, bz, wlds); o0.x = r.x; o0.y = r.y; }
    { const f32x2 r = coop_interp<4, 20,   8>(x0, x1, x2, bx, by, bz, wlds); o0.z = r.x; o0.w = r.y; }
    { const f32x2 r = coop_interp<4, 25,  72>(x0, x1, x2, bx, by, bz, wlds); o1.x = r.x; o1.y = r.y; }
    { const f32x2 r = coop_interp<3, 32, 136>(x0, x1, x2, bx, by, bz, wlds); o1.z = r.x; o1.w = r.y; }
    { const f32x2 r = coop_interp<5, 40, 163>(x0, x1, x2, bx, by, bz, wlds); o2.x = r.x; o2.y = r.y; }
    { const f32x2 r = coop_interp<6, 50, 288>(x0, x1, x2, bx, by, bz, wlds); o2.z = r.x; o2.w = r.y; }
    { const f32x2 r = coop_interp<5, 64, 504>(x0, x1, x2, bx, by, bz, wlds); o3.x = r.x; o3.y = r.y; }
    { const f32x2 r = coop_interp<6, 80, 629>(x0, x1, x2, bx, by, bz, wlds); o3.z = r.x; o3.w = r.y; }

    if (valid) {
        f32x4* op = out + (size_t)__float_as_uint(v.w) * 8;
        __builtin_nontemporal_store(o0, op + 0);
        __builtin_nontemporal_store(o1, op + 1);
        __builtin_nontemporal_store(o2, op + 2);
        __builtin_nontemporal_store(o3, op + 3);
    }
}

// Overflow cleanup in its own dispatch (~always zero work; correctness net).
__global__ __launch_bounds__(256) void cleanup_kernel(const f32x4* __restrict__ ovf,
                                                      const unsigned* __restrict__ cnt,
                                                      const f32x4* __restrict__ tab4base,
                                                      f32x4* __restrict__ out) {
    const unsigned oc = min(cnt[kBins], (unsigned)kOvfCap);
    for (unsigned j = threadIdx.x; j < oc; j += 256) {
        const f32x4 v = ovf[j];
        hashenc_body(v.x, v.y, v.z, tab4base, out, __float_as_uint(v.w));
    }
}

__global__ __launch_bounds__(256, 4) void hashenc_direct(const float* __restrict__ x,
                                                         const f32x4* __restrict__ tab4base,
                                                         f32x4* __restrict__ out) {
    const int i = blockIdx.x * 256 + threadIdx.x;
    hashenc_body(x[3 * i], x[3 * i + 1], x[3 * i + 2], tab4base, out, (unsigned)i);
}

extern "C" void kernel_launch(void* const* d_in, const int* in_sizes, int n_in,
                              void* d_out, int out_size, void* d_ws, size_t ws_size,
                              hipStream_t stream) {
    const float*  x    = (const float*)d_in[0];
    const f32x2*  tab2 = (const f32x2*)d_in[1];
    const f32x4*  tab4 = (const f32x4*)d_in[1];
    f32x4*        out  = (f32x4*)d_out;

    const size_t cntBytes   = (size_t)(kBins + 16) * 4;       // counters + ovf count
    const size_t ovfBytes   = (size_t)kOvfCap * 16;           // 1 MB
    const size_t xsortBytes = (size_t)kBins * kCap * 16;      // 8 MB
    const size_t need = cntBytes + ovfBytes + xsortBytes;

    if (ws_size >= need) {
        unsigned* cnt   = (unsigned*)d_ws;
        f32x4*    ovf   = (f32x4*)((char*)d_ws + cntBytes);
        f32x4*    xsort = ovf + kOvfCap;
        hipMemsetAsync(cnt, 0, cntBytes, stream);
        scatter_kernel<<<kB / 256, 256, 0, stream>>>(x, cnt, xsort, ovf);
        hashenc_main<<<4096, 256, 0, stream>>>(x, xsort, cnt, tab2, tab4, out);
        cleanup_kernel<<<1, 256, 0, stream>>>(ovf, cnt, tab4, out);
    } else {
        hashenc_direct<<<kB / 256, 256, 0, stream>>>(x, tab4, out);
    }
}